// Round 8
// baseline (452.554 us; speedup 1.0000x reference)
//
#include <hip/hip_runtime.h>
#include <math.h>

#define HID 2048
#define NB  2
#define SEQ 2048
#define NT  (NB*SEQ)   // 4096 tokens
#define NH  16
#define HD  128

typedef __attribute__((ext_vector_type(8))) _Float16       f16x8;  // 8 f16 (4 VGPRs)
typedef __attribute__((ext_vector_type(4))) float          f32x4;  // 4 fp32 acc

// softmax scale folded with log2(e): scores in log2 domain -> exp2f.
#define QSCALE 0.12751742f   // (1/sqrt(128)) * log2(e)

__device__ __forceinline__ unsigned short f2h(float x) {   // fp32 -> fp16 (RNE)
    union { _Float16 h; unsigned short u; } c;
    c.h = (_Float16)x;
    return c.u;
}

// ---------------------------------------------------------------------------
// Cast: fp32 -> fp16, one dispatch for all 5 tensors.
// ---------------------------------------------------------------------------
extern "C" __global__ __launch_bounds__(256)
void cast_all(const float* __restrict__ X,
              const float* __restrict__ w0, const float* __restrict__ w1,
              const float* __restrict__ w2, const float* __restrict__ w3,
              unsigned short* __restrict__ Xd,
              unsigned short* __restrict__ d0, unsigned short* __restrict__ d1,
              unsigned short* __restrict__ d2, unsigned short* __restrict__ d3,
              int n4x, int n4w)
{
    const int y = blockIdx.y;
    const float* __restrict__ src =
        (y==0) ? X : (y==1) ? w0 : (y==2) ? w1 : (y==3) ? w2 : w3;
    unsigned short* __restrict__ dst =
        (y==0) ? Xd : (y==1) ? d0 : (y==2) ? d1 : (y==3) ? d2 : d3;
    const int n4 = (y==0) ? n4x : n4w;
    const int i = blockIdx.x * 256 + threadIdx.x;
    if (i >= n4) return;
    const float4 x = ((const float4*)src)[i];
    ushort4 h;
    h.x = f2h(x.x); h.y = f2h(x.y); h.z = f2h(x.z); h.w = f2h(x.w);
    ((ushort4*)dst)[i] = h;
}

// ---------------------------------------------------------------------------
// Kernel 1: fused QKV projection, single-pass fp16 MFMA (proven 139-146 us).
//   Q -> [B,H,S,D] f16 pre-scaled by QSCALE
//   K -> [B,H,S,D] f16
//   V -> [B,H,D,S] f16 (plain transpose; sigma permute dropped — attn's P is
//        now stored in plain s-order)
// ---------------------------------------------------------------------------
extern "C" __global__ __launch_bounds__(256)
void qkv_f16(const unsigned short* __restrict__ Xh,
             const unsigned short* __restrict__ Wqh,
             const unsigned short* __restrict__ Wkh,
             const unsigned short* __restrict__ Wvh,
             const float* __restrict__ bq, const float* __restrict__ bk,
             const float* __restrict__ bv,
             unsigned short* __restrict__ Qb, unsigned short* __restrict__ Kb,
             unsigned short* __restrict__ Vb)
{
    const int on0 = blockIdx.x * 128;
    const int tm0 = blockIdx.y * 128;
    const int which = blockIdx.z;
    const unsigned short* __restrict__ W = (which==0) ? Wqh : (which==1) ? Wkh : Wvh;
    const float* __restrict__ bias      = (which==0) ? bq  : (which==1) ? bk  : bv;

    __shared__ unsigned short Ah[8192], Bh[8192];   // 2 x 16 KB

    const int tid  = threadIdx.x;
    const int lane = tid & 63;
    const int w    = tid >> 6;
    const int wm   = (w & 1) * 64;
    const int wn   = (w >> 1) * 64;
    const int fr   = lane & 15;
    const int quad = lane >> 4;

    f32x4 acc[4][4];
    #pragma unroll
    for (int i = 0; i < 4; ++i)
        #pragma unroll
        for (int j = 0; j < 4; ++j)
            acc[i][j] = (f32x4){0.f, 0.f, 0.f, 0.f};

    for (int kb = 0; kb < HID/64; ++kb) {
        __syncthreads();
        const unsigned short* Asrc = Xh + (size_t)tm0*HID + kb*64;
        const unsigned short* Bsrc = W  + (size_t)on0*HID + kb*64;
        #pragma unroll
        for (int r = 0; r < 4; ++r) {
            const int p   = (r*4 + w)*64 + lane;     // chunk 0..1023
            const int row = p >> 3;
            const int c   = (p & 7) ^ (row & 7);
            __builtin_amdgcn_global_load_lds(
                (const __attribute__((address_space(1))) void*)(Asrc + (size_t)row*HID + c*8),
                (__attribute__((address_space(3))) void*)(Ah + (r*4 + w)*512), 16, 0, 0);
            __builtin_amdgcn_global_load_lds(
                (const __attribute__((address_space(1))) void*)(Bsrc + (size_t)row*HID + c*8),
                (__attribute__((address_space(3))) void*)(Bh + (r*4 + w)*512), 16, 0, 0);
        }
        __syncthreads();

        #pragma unroll
        for (int kk = 0; kk < 2; ++kk) {
            f16x8 a[4], b[4];
            #pragma unroll
            for (int i = 0; i < 4; ++i) {
                const int ra = wm + i*16 + fr;
                a[i] = *(const f16x8*)(Ah + (ra*8 + ((kk*4 + quad) ^ (ra & 7)))*8);
                const int rb = wn + i*16 + fr;
                b[i] = *(const f16x8*)(Bh + (rb*8 + ((kk*4 + quad) ^ (rb & 7)))*8);
            }
            #pragma unroll
            for (int i = 0; i < 4; ++i)
                #pragma unroll
                for (int j = 0; j < 4; ++j)
                    acc[i][j] = __builtin_amdgcn_mfma_f32_16x16x32_f16(a[i], b[j], acc[i][j], 0, 0, 0);
        }
    }

    // epilogue: C layout col=lane&15, row=quad*4+reg
    const int col_l = fr;
    if (which == 2) {
        #pragma unroll
        for (int j = 0; j < 4; ++j) {
            const int o = on0 + wn + j*16 + col_l;
            const float bb = bias[o];
            const int h = o >> 7, d = o & (HD-1);
            #pragma unroll
            for (int i = 0; i < 4; ++i)
                #pragma unroll
                for (int rg = 0; rg < 4; ++rg) {
                    const int t = tm0 + wm + i*16 + quad*4 + rg;
                    const int b = t >> 11, s = t & (SEQ-1);
                    Vb[((size_t)(b*NH + h)*HD + d)*SEQ + s] = f2h(acc[i][j][rg] + bb);
                }
        }
    } else {
        const float sc = (which == 0) ? QSCALE : 1.0f;
        unsigned short* __restrict__ dstp = (which == 0) ? Qb : Kb;
        #pragma unroll
        for (int j = 0; j < 4; ++j) {
            const int o = on0 + wn + j*16 + col_l;
            const float bb = bias[o];
            const int h = o >> 7, d = o & (HD-1);
            #pragma unroll
            for (int i = 0; i < 4; ++i)
                #pragma unroll
                for (int rg = 0; rg < 4; ++rg) {
                    const int t = tm0 + wm + i*16 + quad*4 + rg;
                    const int b = t >> 11, s = t & (SEQ-1);
                    dstp[((size_t)(b*NH + h)*SEQ + s)*HD + d] =
                        f2h((acc[i][j][rg] + bb) * sc);
                }
        }
    }
}

// ---------------------------------------------------------------------------
// Kernel 2: MFMA flash attention, v5 — split-operand waves + hidden staging.
// Diagnosis: v4 was LDS-BW-bound (each of 8 waves read the FULL K and V tile:
// 34 b128/wave/tile = 272 KB read per 32 KB staged).  v5 wave = (iq, j):
// iq = q-quarter (32 rows), j = s-half for QK (reads only 32 K-rows) and
// d-half for PV (reads only 64 V-rows).  P is a block-shared LDS buffer
// [128q][64s] plain s-order, granule-XOR-swizzled by (q&7); PV reads it as
// the A-operand (b128 along s).  Net LDS reads 160 KB/tile (1.7x less).
// K/V double-buffered (80 KB total, 2 blocks/CU): stage(t+1) issued at TOP
// of iter, vmcnt(0) deferred to the BOTTOM raw s_barrier — staging hides
// under QK+SM+PV (~800cy > HBM latency).  2 s_barriers/tile (P-visibility,
// buffer rotate).  Row-sum l: intra-wave shfl + cross-wave pair reduce.
// Output token-major Of[t][HID].
// ---------------------------------------------------------------------------
extern "C" __global__ __launch_bounds__(512, 4)
void attn_mfma(const unsigned short* __restrict__ Qg, const unsigned short* __restrict__ Kg,
               const unsigned short* __restrict__ Vtg, unsigned short* __restrict__ Of)
{
    const int L  = blockIdx.x;
    const int q0 = (L >> 5) * 128;
    const int bh = ((L & 7) << 2) | ((L >> 3) & 3);
    const unsigned short* __restrict__ Qp = Qg  + (size_t)bh * SEQ * HD;
    const unsigned short* __restrict__ Kp = Kg  + (size_t)bh * SEQ * HD;
    const unsigned short* __restrict__ Vp = Vtg + (size_t)bh * HD * SEQ;

    __shared__ alignas(16) unsigned short Ks[2][64*128];   // 32 KB [s][d] dbuf
    __shared__ alignas(16) unsigned short Vts[2][128*64];  // 32 KB [d][s] dbuf
    __shared__ alignas(16) unsigned short Ps[128*64];      // 16 KB [q][s-swz]

    const int tid  = threadIdx.x;
    const int lane = tid & 63;
    const int w    = tid >> 6;       // 0..7
    const int iq   = w >> 1;         // 0..3: q-quarter (32 rows)
    const int js   = w & 1;          // s-half (QK) / d-half (PV)
    const int fr   = lane & 15;
    const int quad = lane >> 4;

    // Q fragments: rows q0 + iq*32 + m*16 + fr
    f16x8 qf[2][4];
    #pragma unroll
    for (int m = 0; m < 2; ++m)
        #pragma unroll
        for (int c = 0; c < 4; ++c)
            qf[m][c] = *(const f16x8*)(Qp + (size_t)(q0 + iq*32 + m*16 + fr)*HD
                                          + c*32 + quad*8);

    f32x4 accO[2][4];
    #pragma unroll
    for (int m = 0; m < 2; ++m)
        #pragma unroll
        for (int n = 0; n < 4; ++n)
            accO[m][n] = (f32x4){0.f, 0.f, 0.f, 0.f};
    float lp[2][4] = {};

#define STAGE(buf, kt_) do {                                                   \
    const unsigned short* _Kt = Kp + (size_t)(kt_)*64*HD;                      \
    _Pragma("unroll")                                                          \
    for (int _r = 0; _r < 2; ++_r) {                                           \
        const int _p = (_r*8 + w)*64 + lane;                                   \
        const int _row = _p >> 4;                                              \
        const int _c = (_p & 15) ^ (_row & 15);                                \
        __builtin_amdgcn_global_load_lds(                                      \
            (const __attribute__((address_space(1))) void*)(_Kt + (size_t)_row*HD + _c*8), \
            (__attribute__((address_space(3))) void*)(&Ks[buf][_p*8]), 16, 0, 0); \
    }                                                                          \
    _Pragma("unroll")                                                          \
    for (int _r = 0; _r < 2; ++_r) {                                           \
        const int _p = (_r*8 + w)*64 + lane;                                   \
        const int _row = _p >> 3;                                              \
        const int _c = (_p & 7) ^ (_row & 7);                                  \
        __builtin_amdgcn_global_load_lds(                                      \
            (const __attribute__((address_space(1))) void*)(Vp + (size_t)_row*SEQ + (kt_)*64 + _c*8), \
            (__attribute__((address_space(3))) void*)(&Vts[buf][_p*8]), 16, 0, 0); \
    } } while (0)

    // prologue: stage tile 0, full drain
    STAGE(0, 0);
    __syncthreads();

    int cur = 0;
    for (int kt = 0; kt < SEQ/64; ++kt) {
        // issue next-tile stage into the other buffer; waited at bottom barrier
        if (kt + 1 < SEQ/64) STAGE(cur ^ 1, kt + 1);

        const unsigned short* Kc = &Ks[cur][0];
        const unsigned short* Vc = &Vts[cur][0];

        // ---- S = Q K^T on this wave's s-half: s = js*32 + n*16 + fr ----
        f32x4 accS[2][2];
        #pragma unroll
        for (int m = 0; m < 2; ++m)
            #pragma unroll
            for (int n = 0; n < 2; ++n)
                accS[m][n] = (f32x4){0.f, 0.f, 0.f, 0.f};
        #pragma unroll
        for (int c = 0; c < 4; ++c) {
            f16x8 bf[2];
            #pragma unroll
            for (int n = 0; n < 2; ++n)
                bf[n] = *(const f16x8*)(Kc + (js*32 + n*16 + fr)*128
                                           + (((c*4 + quad) ^ fr) << 3));
            __builtin_amdgcn_s_setprio(1);
            #pragma unroll
            for (int m = 0; m < 2; ++m)
                #pragma unroll
                for (int n = 0; n < 2; ++n)
                    accS[m][n] = __builtin_amdgcn_mfma_f32_16x16x32_f16(
                        qf[m][c], bf[n], accS[m][n], 0, 0, 0);
            __builtin_amdgcn_s_setprio(0);
        }

        // ---- P = exp2(S) -> shared Ps[q][s] (granule ^ (q&7)) ----
        #pragma unroll
        for (int m = 0; m < 2; ++m)
            #pragma unroll
            for (int n = 0; n < 2; ++n)
                #pragma unroll
                for (int rg = 0; rg < 4; ++rg) {
                    const float p = exp2f(accS[m][n][rg]);
                    lp[m][rg] += p;
                    const int q = iq*32 + m*16 + quad*4 + rg;
                    const int s = js*32 + n*16 + fr;
                    Ps[q*64 + ((((s >> 3) ^ (q & 7)) << 3) | (s & 7))] = f2h(p);
                }
        asm volatile("s_waitcnt lgkmcnt(0)" ::: "memory");
        __builtin_amdgcn_s_barrier();          // P visible to all waves
        __builtin_amdgcn_sched_barrier(0);

        // ---- O += P @ V on this wave's d-half: d = js*64 + n*16 + fr ----
        #pragma unroll
        for (int kk = 0; kk < 2; ++kk) {
            f16x8 pf[2], vf[4];
            #pragma unroll
            for (int m = 0; m < 2; ++m)
                pf[m] = *(const f16x8*)(Ps + (iq*32 + m*16 + fr)*64
                                           + (((kk*4 + quad) ^ (fr & 7)) << 3));
            #pragma unroll
            for (int n = 0; n < 4; ++n)
                vf[n] = *(const f16x8*)(Vc + (js*64 + n*16 + fr)*64
                                           + (((kk*4 + quad) ^ (fr & 7)) << 3));
            __builtin_amdgcn_s_setprio(1);
            #pragma unroll
            for (int m = 0; m < 2; ++m)
                #pragma unroll
                for (int n = 0; n < 4; ++n)
                    accO[m][n] = __builtin_amdgcn_mfma_f32_16x16x32_f16(
                        pf[m], vf[n], accO[m][n], 0, 0, 0);
            __builtin_amdgcn_s_setprio(0);
        }

        // bottom: stage(t+1) landed (issued ~full tile ago); P/V reads done
        asm volatile("s_waitcnt vmcnt(0) lgkmcnt(0)" ::: "memory");
        __builtin_amdgcn_s_barrier();
        __builtin_amdgcn_sched_barrier(0);
        cur ^= 1;
    }
#undef STAGE

    // ---- epilogue: l = intra-wave fr-reduce + cross-wave (js pair) ----
    float lred[2][4];
    #pragma unroll
    for (int m = 0; m < 2; ++m)
        #pragma unroll
        for (int rg = 0; rg < 4; ++rg) {
            float l = lp[m][rg];
            l += __shfl_xor(l, 1);
            l += __shfl_xor(l, 2);
            l += __shfl_xor(l, 4);
            l += __shfl_xor(l, 8);
            lred[m][rg] = l;
        }
    float* Ls = (float*)(&Ks[0][0]);           // reuse K buffer (post-barrier)
    if (fr == 0) {
        #pragma unroll
        for (int m = 0; m < 2; ++m)
            #pragma unroll
            for (int rg = 0; rg < 4; ++rg)
                Ls[w*32 + m*16 + quad*4 + rg] = lred[m][rg];
    }
    __syncthreads();

    const int bb_ = bh >> 4;         // batch
    const int hh_ = bh & (NH - 1);   // head
    #pragma unroll
    for (int m = 0; m < 2; ++m) {
        float inv[4];
        #pragma unroll
        for (int rg = 0; rg < 4; ++rg)
            inv[rg] = 1.0f / (lred[m][rg] + Ls[(w ^ 1)*32 + m*16 + quad*4 + rg]);
        #pragma unroll
        for (int n = 0; n < 4; ++n) {
            const int d = js*64 + n*16 + fr;
            #pragma unroll
            for (int rg = 0; rg < 4; ++rg) {
                const int s = q0 + iq*32 + m*16 + quad*4 + rg;
                Of[((size_t)(bb_*SEQ + s))*HID + hh_*HD + d] = f2h(accO[m][n][rg] * inv[rg]);
            }
        }
    }
}

// ---------------------------------------------------------------------------
// Kernel 3: output projection.  BM=64 x BN=128 tile, 256 threads (4 waves x
// 32x64), grid 1024 blocks, 24 KB LDS.  A token-major [t][HID] f16.
// ---------------------------------------------------------------------------
extern "C" __global__ __launch_bounds__(256)
void oproj_f16(const unsigned short* __restrict__ Af,
               const unsigned short* __restrict__ Woh,
               const float* __restrict__ bo, float* __restrict__ Y)
{
    const int on0 = blockIdx.x * 128;
    const int tm0 = blockIdx.y * 64;

    __shared__ unsigned short Ah[4096], Bh[8192];   // 8 KB + 16 KB

    const int tid  = threadIdx.x;
    const int lane = tid & 63;
    const int w    = tid >> 6;      // 0..3
    const int wm   = (w & 1) * 32;  // 0,32
    const int wn   = (w >> 1) * 64; // 0,64
    const int fr   = lane & 15;
    const int quad = lane >> 4;

    f32x4 acc[2][4];
    #pragma unroll
    for (int i = 0; i < 2; ++i)
        #pragma unroll
        for (int j = 0; j < 4; ++j)
            acc[i][j] = (f32x4){0.f, 0.f, 0.f, 0.f};

    for (int kb = 0; kb < HID/64; ++kb) {
        __syncthreads();
        const unsigned short* Asrc = Af  + (size_t)tm0*HID + kb*64;
        const unsigned short* Bsrc = Woh + (size_t)on0*HID + kb*64;
        #pragma unroll
        for (int r = 0; r < 2; ++r) {       // A: 64x64 = 512 chunks
            const int p   = r*256 + tid;
            const int row = p >> 3;
            const int c   = (p & 7) ^ (row & 7);
            __builtin_amdgcn_global_load_lds(
                (const __attribute__((address_space(1))) void*)(Asrc + (size_t)row*HID + c*8),
                (__attribute__((address_space(3))) void*)(Ah + p*8), 16, 0, 0);
        }
        #pragma unroll
        for (int r = 0; r < 4; ++r) {       // B: 128x64 = 1024 chunks
            const int p   = r*256 + tid;
            const int row = p >> 3;
            const int c   = (p & 7) ^ (row & 7);
            __builtin_amdgcn_global_load_lds(
                (const __attribute__((address_space(1))) void*)(Bsrc + (size_t)row*HID + c*8),
                (__attribute__((address_space(3))) void*)(Bh + p*8), 16, 0, 0);
        }
        __syncthreads();

        #pragma unroll
        for (int kk = 0; kk < 2; ++kk) {
            f16x8 a[2], b[4];
            #pragma unroll
            for (int i = 0; i < 2; ++i) {
                const int ra = wm + i*16 + fr;
                a[i] = *(const f16x8*)(Ah + (ra*8 + ((kk*4 + quad) ^ (ra & 7)))*8);
            }
            #pragma unroll
            for (int j = 0; j < 4; ++j) {
                const int rb = wn + j*16 + fr;
                b[j] = *(const f16x8*)(Bh + (rb*8 + ((kk*4 + quad) ^ (rb & 7)))*8);
            }
            #pragma unroll
            for (int i = 0; i < 2; ++i)
                #pragma unroll
                for (int j = 0; j < 4; ++j)
                    acc[i][j] = __builtin_amdgcn_mfma_f32_16x16x32_f16(a[i], b[j], acc[i][j], 0, 0, 0);
        }
    }

    #pragma unroll
    for (int j = 0; j < 4; ++j) {
        const int o = on0 + wn + j*16 + fr;
        const float bb = bo[o];
        #pragma unroll
        for (int i = 0; i < 2; ++i)
            #pragma unroll
            for (int rg = 0; rg < 4; ++rg) {
                const int t = tm0 + wm + i*16 + quad*4 + rg;
                Y[(size_t)t*HID + o] = acc[i][j][rg] + bb;
            }
    }
}

// ---------------------------------------------------------------------------
// Launch.  Workspace (ushort units, 117 MB):
//   Qb,Kb f16 [B,H,S,D]; Vb f16 [B,H,D,S] (plain transpose)
//   Of f16 [t][HID] token-major (attn output)
//   Xh f16; Wq/Wk/Wv/Wo f16
// ---------------------------------------------------------------------------
extern "C" void kernel_launch(void* const* d_in, const int* in_sizes, int n_in,
                              void* d_out, int out_size, void* d_ws, size_t ws_size,
                              hipStream_t stream)
{
    const float* X  = (const float*)d_in[0];
    const float* wq = (const float*)d_in[1];
    const float* bq = (const float*)d_in[2];
    const float* wk = (const float*)d_in[3];
    const float* bk = (const float*)d_in[4];
    const float* wv = (const float*)d_in[5];
    const float* bv = (const float*)d_in[6];
    const float* wo = (const float*)d_in[7];
    const float* bo = (const float*)d_in[8];
    float* Y = (float*)d_out;

    const size_t F  = (size_t)NT * HID;    // 8,388,608
    const size_t Wn = (size_t)HID * HID;   // 4,194,304

    unsigned short* Qb  = (unsigned short*)d_ws;
    unsigned short* Kb  = Qb  + F;
    unsigned short* Vb  = Kb  + F;     // [B,H,D,S]
    unsigned short* Of  = Vb  + F;     // token-major [t][HID]
    unsigned short* Xh  = Of  + F;
    unsigned short* Wqh = Xh  + F;
    unsigned short* Wkh = Wqh + Wn;
    unsigned short* Wvh = Wkh + Wn;
    unsigned short* Woh = Wvh + Wn;

    const int n4x = (int)(F/4);    // 2,097,152
    const int n4w = (int)(Wn/4);   // 1,048,576

    cast_all<<<dim3((n4x + 255)/256, 5), 256, 0, stream>>>(
        X, wq, wk, wv, wo, Xh, Wqh, Wkh, Wvh, Woh, n4x, n4w);

    qkv_f16<<<dim3(HID/128, NT/128, 3), 256, 0, stream>>>(
        Xh, Wqh, Wkh, Wvh, bq, bk, bv, Qb, Kb, Vb);

    attn_mfma<<<dim3(512, 1, 1), 512, 0, stream>>>(Qb, Kb, Vb, Of);

    oproj_f16<<<dim3(HID/128, NT/64), 256, 0, stream>>>(Of, Woh, bo, Y);
}

// Round 9
// 426.260 us; speedup vs baseline: 1.0617x; 1.0617x over previous
//
#include <hip/hip_runtime.h>
#include <math.h>

#define HID 2048
#define NB  2
#define SEQ 2048
#define NT  (NB*SEQ)   // 4096 tokens
#define NH  16
#define HD  128

typedef __attribute__((ext_vector_type(8))) _Float16       f16x8;  // 8 f16 (4 VGPRs)
typedef __attribute__((ext_vector_type(2))) __fp16         h16x2;  // cvt_pkrtz result
typedef __attribute__((ext_vector_type(4))) float          f32x4;  // 4 fp32 acc

// softmax scale folded with log2(e): scores in log2 domain -> exp2f.
#define QSCALE 0.12751742f   // (1/sqrt(128)) * log2(e)

__device__ __forceinline__ unsigned short f2h(float x) {   // fp32 -> fp16 (RNE)
    union { _Float16 h; unsigned short u; } c;
    c.h = (_Float16)x;
    return c.u;
}

// sigma' permutation within each 64-block of s (matches attn v6 P packing):
// fr = s&15, n = (s>>4)&1, js = (s>>5)&1  ->  s' = fr*4 + js*2 + n
__device__ __forceinline__ int sigmap(int s) {
    return (s & ~63) | (((s & 15) << 2) | (((s >> 5) & 1) << 1) | ((s >> 4) & 1));
}

// ---------------------------------------------------------------------------
// Cast: fp32 -> fp16, one dispatch for all 5 tensors.
// ---------------------------------------------------------------------------
extern "C" __global__ __launch_bounds__(256)
void cast_all(const float* __restrict__ X,
              const float* __restrict__ w0, const float* __restrict__ w1,
              const float* __restrict__ w2, const float* __restrict__ w3,
              unsigned short* __restrict__ Xd,
              unsigned short* __restrict__ d0, unsigned short* __restrict__ d1,
              unsigned short* __restrict__ d2, unsigned short* __restrict__ d3,
              int n4x, int n4w)
{
    const int y = blockIdx.y;
    const float* __restrict__ src =
        (y==0) ? X : (y==1) ? w0 : (y==2) ? w1 : (y==3) ? w2 : w3;
    unsigned short* __restrict__ dst =
        (y==0) ? Xd : (y==1) ? d0 : (y==2) ? d1 : (y==3) ? d2 : d3;
    const int n4 = (y==0) ? n4x : n4w;
    const int i = blockIdx.x * 256 + threadIdx.x;
    if (i >= n4) return;
    const float4 x = ((const float4*)src)[i];
    ushort4 h;
    h.x = f2h(x.x); h.y = f2h(x.y); h.z = f2h(x.z); h.w = f2h(x.w);
    ((ushort4*)dst)[i] = h;
}

// ---------------------------------------------------------------------------
// Kernel 1: fused QKV projection, single-pass fp16 MFMA (proven 139-146 us).
//   Q -> [B,H,S,D] f16 pre-scaled by QSCALE
//   K -> [B,H,S,D] f16
//   V -> [B,H,D,S'] f16, s' sigma'-permuted within 64-blocks (see sigmap).
// ---------------------------------------------------------------------------
extern "C" __global__ __launch_bounds__(256)
void qkv_f16(const unsigned short* __restrict__ Xh,
             const unsigned short* __restrict__ Wqh,
             const unsigned short* __restrict__ Wkh,
             const unsigned short* __restrict__ Wvh,
             const float* __restrict__ bq, const float* __restrict__ bk,
             const float* __restrict__ bv,
             unsigned short* __restrict__ Qb, unsigned short* __restrict__ Kb,
             unsigned short* __restrict__ Vb)
{
    const int on0 = blockIdx.x * 128;
    const int tm0 = blockIdx.y * 128;
    const int which = blockIdx.z;
    const unsigned short* __restrict__ W = (which==0) ? Wqh : (which==1) ? Wkh : Wvh;
    const float* __restrict__ bias      = (which==0) ? bq  : (which==1) ? bk  : bv;

    __shared__ unsigned short Ah[8192], Bh[8192];   // 2 x 16 KB

    const int tid  = threadIdx.x;
    const int lane = tid & 63;
    const int w    = tid >> 6;
    const int wm   = (w & 1) * 64;
    const int wn   = (w >> 1) * 64;
    const int fr   = lane & 15;
    const int quad = lane >> 4;

    f32x4 acc[4][4];
    #pragma unroll
    for (int i = 0; i < 4; ++i)
        #pragma unroll
        for (int j = 0; j < 4; ++j)
            acc[i][j] = (f32x4){0.f, 0.f, 0.f, 0.f};

    for (int kb = 0; kb < HID/64; ++kb) {
        __syncthreads();
        const unsigned short* Asrc = Xh + (size_t)tm0*HID + kb*64;
        const unsigned short* Bsrc = W  + (size_t)on0*HID + kb*64;
        #pragma unroll
        for (int r = 0; r < 4; ++r) {
            const int p   = (r*4 + w)*64 + lane;     // chunk 0..1023
            const int row = p >> 3;
            const int c   = (p & 7) ^ (row & 7);
            __builtin_amdgcn_global_load_lds(
                (const __attribute__((address_space(1))) void*)(Asrc + (size_t)row*HID + c*8),
                (__attribute__((address_space(3))) void*)(Ah + (r*4 + w)*512), 16, 0, 0);
            __builtin_amdgcn_global_load_lds(
                (const __attribute__((address_space(1))) void*)(Bsrc + (size_t)row*HID + c*8),
                (__attribute__((address_space(3))) void*)(Bh + (r*4 + w)*512), 16, 0, 0);
        }
        __syncthreads();

        #pragma unroll
        for (int kk = 0; kk < 2; ++kk) {
            f16x8 a[4], b[4];
            #pragma unroll
            for (int i = 0; i < 4; ++i) {
                const int ra = wm + i*16 + fr;
                a[i] = *(const f16x8*)(Ah + (ra*8 + ((kk*4 + quad) ^ (ra & 7)))*8);
                const int rb = wn + i*16 + fr;
                b[i] = *(const f16x8*)(Bh + (rb*8 + ((kk*4 + quad) ^ (rb & 7)))*8);
            }
            #pragma unroll
            for (int i = 0; i < 4; ++i)
                #pragma unroll
                for (int j = 0; j < 4; ++j)
                    acc[i][j] = __builtin_amdgcn_mfma_f32_16x16x32_f16(a[i], b[j], acc[i][j], 0, 0, 0);
        }
    }

    // epilogue: C layout col=lane&15, row=quad*4+reg
    const int col_l = fr;
    if (which == 2) {
        #pragma unroll
        for (int j = 0; j < 4; ++j) {
            const int o = on0 + wn + j*16 + col_l;
            const float bb = bias[o];
            const int h = o >> 7, d = o & (HD-1);
            #pragma unroll
            for (int i = 0; i < 4; ++i)
                #pragma unroll
                for (int rg = 0; rg < 4; ++rg) {
                    const int t = tm0 + wm + i*16 + quad*4 + rg;
                    const int b = t >> 11, s = t & (SEQ-1);
                    const int pos = sigmap(s);
                    Vb[((size_t)(b*NH + h)*HD + d)*SEQ + pos] = f2h(acc[i][j][rg] + bb);
                }
        }
    } else {
        const float sc = (which == 0) ? QSCALE : 1.0f;
        unsigned short* __restrict__ dstp = (which == 0) ? Qb : Kb;
        #pragma unroll
        for (int j = 0; j < 4; ++j) {
            const int o = on0 + wn + j*16 + col_l;
            const float bb = bias[o];
            const int h = o >> 7, d = o & (HD-1);
            #pragma unroll
            for (int i = 0; i < 4; ++i)
                #pragma unroll
                for (int rg = 0; rg < 4; ++rg) {
                    const int t = tm0 + wm + i*16 + quad*4 + rg;
                    const int b = t >> 11, s = t & (SEQ-1);
                    dstp[((size_t)(b*NH + h)*SEQ + s)*HD + d] =
                        f2h((acc[i][j][rg] + bb) * sc);
                }
        }
    }
}

// ---------------------------------------------------------------------------
// Kernel 2: MFMA flash attention, v6 — split-operand waves on the proven R7
// skeleton.  Diagnosis: R7 was LDS-BW-bound (34 ds_read_b128/thread/tile ~
// 7300 LDS cy/CU/tile ~ the whole runtime).  v6 wave = (iq, js): iq = q-
// quarter (32 rows), js = s-half in QK (reads 32 of 64 K-rows) and d-half in
// PV (reads 64 of 128 V-rows) -> 20 b128/thread/tile (1.6x less).
// P is block-shared Ps[128][72] in sigma' order (s' = fr*4 + js*2 + n):
// packed ushort2 cvt_pkrtz stores (8/thread), b128 reads 16B-aligned
// (stride 144 B = 9x16), banks <= 2-way.  V stored sigma' by qkv so PV's
// existing granule-XOR fragment reads stay correct.  Staging: R7's single-
// buffered global_load_lds + __syncthreads (v5's raw-barrier/manual-waitcnt
// discipline regressed; m141 pattern).  3 syncs/tile (stage-done, P-visible,
// reads-done).  l: intra-wave shfl + cross-wave (js pair) via LDS.
// Output token-major Of[t][HID].
// ---------------------------------------------------------------------------
#define PS_STRIDE 72   // 64 + 8 pad; 144 B = 9*16 B (b128-aligned rows)

extern "C" __global__ __launch_bounds__(512, 4)
void attn_mfma(const unsigned short* __restrict__ Qg, const unsigned short* __restrict__ Kg,
               const unsigned short* __restrict__ Vtg, unsigned short* __restrict__ Of)
{
    const int L  = blockIdx.x;
    const int q0 = (L >> 5) * 128;
    const int bh = ((L & 7) << 2) | ((L >> 3) & 3);
    const unsigned short* __restrict__ Qp = Qg  + (size_t)bh * SEQ * HD;
    const unsigned short* __restrict__ Kp = Kg  + (size_t)bh * SEQ * HD;
    const unsigned short* __restrict__ Vp = Vtg + (size_t)bh * HD * SEQ;

    __shared__ alignas(16) unsigned short Ks[64*128];          // 16 KB [s][d]
    __shared__ alignas(16) unsigned short Vts[128*64];         // 16 KB [d][s']
    __shared__ alignas(16) unsigned short Ps[128*PS_STRIDE];   // 18 KB [q][s']

    const int tid  = threadIdx.x;
    const int lane = tid & 63;
    const int w    = tid >> 6;       // 0..7
    const int iq   = w >> 1;         // q-quarter (32 rows)
    const int js   = w & 1;          // s-half (QK) / d-half (PV)
    const int fr   = lane & 15;
    const int quad = lane >> 4;

    // Q fragments: rows q0 + iq*32 + m*16 + fr
    f16x8 qf[2][4];
    #pragma unroll
    for (int m = 0; m < 2; ++m)
        #pragma unroll
        for (int c = 0; c < 4; ++c)
            qf[m][c] = *(const f16x8*)(Qp + (size_t)(q0 + iq*32 + m*16 + fr)*HD
                                          + c*32 + quad*8);

    f32x4 accO[2][4];
    #pragma unroll
    for (int m = 0; m < 2; ++m)
        #pragma unroll
        for (int n = 0; n < 4; ++n)
            accO[m][n] = (f32x4){0.f, 0.f, 0.f, 0.f};
    float lp[2][4] = {};

    for (int kt = 0; kt < SEQ/64; ++kt) {
        __syncthreads();                       // prior reads of Ks/Vts/Ps done
        {
            const unsigned short* Kt = Kp + (size_t)kt*64*HD;
            #pragma unroll
            for (int r = 0; r < 2; ++r) {
                const int p   = (r*8 + w)*64 + lane;   // 0..1023
                const int row = p >> 4;
                const int c   = (p & 15) ^ (row & 15);
                __builtin_amdgcn_global_load_lds(
                    (const __attribute__((address_space(1))) void*)(Kt + (size_t)row*HD + c*8),
                    (__attribute__((address_space(3))) void*)(Ks + (r*8 + w)*512), 16, 0, 0);
            }
            #pragma unroll
            for (int r = 0; r < 2; ++r) {
                const int p   = (r*8 + w)*64 + lane;
                const int row = p >> 3;                // d 0..127
                const int c   = (p & 7) ^ (row & 7);
                __builtin_amdgcn_global_load_lds(
                    (const __attribute__((address_space(1))) void*)(Vp + (size_t)row*SEQ + kt*64 + c*8),
                    (__attribute__((address_space(3))) void*)(Vts + (r*8 + w)*512), 16, 0, 0);
            }
        }
        __syncthreads();                       // staging complete

        // ---- S = Q K^T on this wave's s-half: s = js*32 + n*16 + fr ----
        f32x4 accS[2][2];
        #pragma unroll
        for (int m = 0; m < 2; ++m)
            #pragma unroll
            for (int n = 0; n < 2; ++n)
                accS[m][n] = (f32x4){0.f, 0.f, 0.f, 0.f};
        #pragma unroll
        for (int c = 0; c < 4; ++c) {
            f16x8 bf[2];
            #pragma unroll
            for (int n = 0; n < 2; ++n) {
                const int row = js*32 + n*16 + fr;
                bf[n] = *(const f16x8*)(Ks + row*128 + (((c*4 + quad) ^ fr) << 3));
            }
            __builtin_amdgcn_s_setprio(1);
            #pragma unroll
            for (int m = 0; m < 2; ++m)
                #pragma unroll
                for (int n = 0; n < 2; ++n)
                    accS[m][n] = __builtin_amdgcn_mfma_f32_16x16x32_f16(
                        qf[m][c], bf[n], accS[m][n], 0, 0, 0);
            __builtin_amdgcn_s_setprio(0);
        }

        // ---- P = exp2(S); packed ushort2 at sigma' position fr*4+js*2 ----
        #pragma unroll
        for (int m = 0; m < 2; ++m)
            #pragma unroll
            for (int rg = 0; rg < 4; ++rg) {
                const float p0 = exp2f(accS[m][0][rg]);
                const float p1 = exp2f(accS[m][1][rg]);
                lp[m][rg] += p0 + p1;
                union { h16x2 h; unsigned int u; } pk;
                pk.h = __builtin_amdgcn_cvt_pkrtz(p0, p1);
                const int qq = iq*32 + m*16 + quad*4 + rg;
                *(unsigned int*)(&Ps[qq*PS_STRIDE + fr*4 + js*2]) = pk.u;
            }
        __syncthreads();                       // P visible to partner waves

        // ---- O += P @ V on this wave's d-half: d = js*64 + n*16 + fr ----
        #pragma unroll
        for (int kk = 0; kk < 2; ++kk) {
            f16x8 pf[2], vf[4];
            #pragma unroll
            for (int m = 0; m < 2; ++m)
                pf[m] = *(const f16x8*)(Ps + (iq*32 + m*16 + fr)*PS_STRIDE
                                           + kk*32 + quad*8);
            #pragma unroll
            for (int n = 0; n < 4; ++n) {
                const int row = js*64 + n*16 + fr;
                vf[n] = *(const f16x8*)(Vts + row*64 + (((kk*4 + quad) ^ (fr & 7)) << 3));
            }
            __builtin_amdgcn_s_setprio(1);
            #pragma unroll
            for (int m = 0; m < 2; ++m)
                #pragma unroll
                for (int n = 0; n < 4; ++n)
                    accO[m][n] = __builtin_amdgcn_mfma_f32_16x16x32_f16(
                        pf[m], vf[n], accO[m][n], 0, 0, 0);
            __builtin_amdgcn_s_setprio(0);
        }
    }

    // ---- epilogue: l = intra-wave fr-reduce + cross-wave (js pair) ----
    float lred[2][4];
    #pragma unroll
    for (int m = 0; m < 2; ++m)
        #pragma unroll
        for (int rg = 0; rg < 4; ++rg) {
            float l = lp[m][rg];
            l += __shfl_xor(l, 1);
            l += __shfl_xor(l, 2);
            l += __shfl_xor(l, 4);
            l += __shfl_xor(l, 8);
            lred[m][rg] = l;
        }
    __syncthreads();                           // done with Ks; reuse for l
    float* Ls = (float*)(&Ks[0]);
    if (fr == 0) {
        #pragma unroll
        for (int m = 0; m < 2; ++m)
            #pragma unroll
            for (int rg = 0; rg < 4; ++rg)
                Ls[w*32 + m*16 + quad*4 + rg] = lred[m][rg];
    }
    __syncthreads();

    const int bb_ = bh >> 4;         // batch
    const int hh_ = bh & (NH - 1);   // head
    #pragma unroll
    for (int m = 0; m < 2; ++m) {
        float inv[4];
        #pragma unroll
        for (int rg = 0; rg < 4; ++rg)
            inv[rg] = 1.0f / (lred[m][rg] + Ls[(w ^ 1)*32 + m*16 + quad*4 + rg]);
        #pragma unroll
        for (int n = 0; n < 4; ++n) {
            const int d = js*64 + n*16 + fr;
            #pragma unroll
            for (int rg = 0; rg < 4; ++rg) {
                const int s = q0 + iq*32 + m*16 + quad*4 + rg;
                Of[((size_t)(bb_*SEQ + s))*HID + hh_*HD + d] = f2h(accO[m][n][rg] * inv[rg]);
            }
        }
    }
}

// ---------------------------------------------------------------------------
// Kernel 3: output projection.  BM=64 x BN=128 tile, 256 threads (4 waves x
// 32x64), grid 1024 blocks, 24 KB LDS.  A token-major [t][HID] f16.
// ---------------------------------------------------------------------------
extern "C" __global__ __launch_bounds__(256)
void oproj_f16(const unsigned short* __restrict__ Af,
               const unsigned short* __restrict__ Woh,
               const float* __restrict__ bo, float* __restrict__ Y)
{
    const int on0 = blockIdx.x * 128;
    const int tm0 = blockIdx.y * 64;

    __shared__ unsigned short Ah[4096], Bh[8192];   // 8 KB + 16 KB

    const int tid  = threadIdx.x;
    const int lane = tid & 63;
    const int w    = tid >> 6;      // 0..3
    const int wm   = (w & 1) * 32;  // 0,32
    const int wn   = (w >> 1) * 64; // 0,64
    const int fr   = lane & 15;
    const int quad = lane >> 4;

    f32x4 acc[2][4];
    #pragma unroll
    for (int i = 0; i < 2; ++i)
        #pragma unroll
        for (int j = 0; j < 4; ++j)
            acc[i][j] = (f32x4){0.f, 0.f, 0.f, 0.f};

    for (int kb = 0; kb < HID/64; ++kb) {
        __syncthreads();
        const unsigned short* Asrc = Af  + (size_t)tm0*HID + kb*64;
        const unsigned short* Bsrc = Woh + (size_t)on0*HID + kb*64;
        #pragma unroll
        for (int r = 0; r < 2; ++r) {       // A: 64x64 = 512 chunks
            const int p   = r*256 + tid;
            const int row = p >> 3;
            const int c   = (p & 7) ^ (row & 7);
            __builtin_amdgcn_global_load_lds(
                (const __attribute__((address_space(1))) void*)(Asrc + (size_t)row*HID + c*8),
                (__attribute__((address_space(3))) void*)(Ah + p*8), 16, 0, 0);
        }
        #pragma unroll
        for (int r = 0; r < 4; ++r) {       // B: 128x64 = 1024 chunks
            const int p   = r*256 + tid;
            const int row = p >> 3;
            const int c   = (p & 7) ^ (row & 7);
            __builtin_amdgcn_global_load_lds(
                (const __attribute__((address_space(1))) void*)(Bsrc + (size_t)row*HID + c*8),
                (__attribute__((address_space(3))) void*)(Bh + p*8), 16, 0, 0);
        }
        __syncthreads();

        #pragma unroll
        for (int kk = 0; kk < 2; ++kk) {
            f16x8 a[2], b[4];
            #pragma unroll
            for (int i = 0; i < 2; ++i) {
                const int ra = wm + i*16 + fr;
                a[i] = *(const f16x8*)(Ah + (ra*8 + ((kk*4 + quad) ^ (ra & 7)))*8);
            }
            #pragma unroll
            for (int j = 0; j < 4; ++j) {
                const int rb = wn + j*16 + fr;
                b[j] = *(const f16x8*)(Bh + (rb*8 + ((kk*4 + quad) ^ (rb & 7)))*8);
            }
            #pragma unroll
            for (int i = 0; i < 2; ++i)
                #pragma unroll
                for (int j = 0; j < 4; ++j)
                    acc[i][j] = __builtin_amdgcn_mfma_f32_16x16x32_f16(a[i], b[j], acc[i][j], 0, 0, 0);
        }
    }

    #pragma unroll
    for (int j = 0; j < 4; ++j) {
        const int o = on0 + wn + j*16 + fr;
        const float bb = bo[o];
        #pragma unroll
        for (int i = 0; i < 2; ++i)
            #pragma unroll
            for (int rg = 0; rg < 4; ++rg) {
                const int t = tm0 + wm + i*16 + quad*4 + rg;
                Y[(size_t)t*HID + o] = acc[i][j][rg] + bb;
            }
    }
}

// ---------------------------------------------------------------------------
// Launch.  Workspace (ushort units, 117 MB):
//   Qb,Kb f16 [B,H,S,D]; Vb f16 [B,H,D,S'] (sigma'-permuted)
//   Of f16 [t][HID] token-major (attn output)
//   Xh f16; Wq/Wk/Wv/Wo f16
// ---------------------------------------------------------------------------
extern "C" void kernel_launch(void* const* d_in, const int* in_sizes, int n_in,
                              void* d_out, int out_size, void* d_ws, size_t ws_size,
                              hipStream_t stream)
{
    const float* X  = (const float*)d_in[0];
    const float* wq = (const float*)d_in[1];
    const float* bq = (const float*)d_in[2];
    const float* wk = (const float*)d_in[3];
    const float* bk = (const float*)d_in[4];
    const float* wv = (const float*)d_in[5];
    const float* bv = (const float*)d_in[6];
    const float* wo = (const float*)d_in[7];
    const float* bo = (const float*)d_in[8];
    float* Y = (float*)d_out;

    const size_t F  = (size_t)NT * HID;    // 8,388,608
    const size_t Wn = (size_t)HID * HID;   // 4,194,304

    unsigned short* Qb  = (unsigned short*)d_ws;
    unsigned short* Kb  = Qb  + F;
    unsigned short* Vb  = Kb  + F;     // [B,H,D,S'] sigma'
    unsigned short* Of  = Vb  + F;     // token-major [t][HID]
    unsigned short* Xh  = Of  + F;
    unsigned short* Wqh = Xh  + F;
    unsigned short* Wkh = Wqh + Wn;
    unsigned short* Wvh = Wkh + Wn;
    unsigned short* Woh = Wvh + Wn;

    const int n4x = (int)(F/4);    // 2,097,152
    const int n4w = (int)(Wn/4);   // 1,048,576

    cast_all<<<dim3((n4x + 255)/256, 5), 256, 0, stream>>>(
        X, wq, wk, wv, wo, Xh, Wqh, Wkh, Wvh, Woh, n4x, n4w);

    qkv_f16<<<dim3(HID/128, NT/128, 3), 256, 0, stream>>>(
        Xh, Wqh, Wkh, Wvh, bq, bk, bv, Qb, Kb, Vb);

    attn_mfma<<<dim3(512, 1, 1), 512, 0, stream>>>(Qb, Kb, Vb, Of);

    oproj_f16<<<dim3(HID/128, NT/64), 256, 0, stream>>>(Of, Woh, bo, Y);
}